// Round 3
// baseline (263.147 us; speedup 1.0000x reference)
//
#include <hip/hip_runtime.h>

// Problem constants (fixed by reference setup_inputs)
#define BB 256          // batch
#define TT 65536        // time
#define LL 32           // chunk length (register-buffered)
#define CC (TT / LL)    // 2048 chunks per row
#define CSH 11          // log2(CC)

// Filter coefficients (a0 = 1)
#define P1f  ( 1.31861375911f)   // -a1
#define P2f  (-0.32059452332f)   // -a2
#define B0f  ( 0.95616638497f)
#define B1f  (-1.31960414122f)
#define B2f  ( 0.36343775625f)

// One IIR step: y = b0*x + b1*x1 + b2*x2 - a1*y1 - a2*y2; shift state.
__device__ __forceinline__ float stepf(float xc, float& x1, float& x2,
                                       float& y1, float& y2) {
    float fir = fmaf(B0f, xc, fmaf(B1f, x1, B2f * x2));
    float y   = fmaf(P1f, y1, fmaf(P2f, y2, fir));
    y2 = y1; y1 = y;
    x2 = x1; x1 = xc;
    return y;
}

// ---------------------------------------------------------------------------
// Pass A: forward local end-states. Thread = (signal-row rs, chunk c).
// Zero y-state, TRUE x taps; emits chunk-exit state (y[last], y[last-1]).
// ---------------------------------------------------------------------------
__global__ __launch_bounds__(256) void k_fwd_states(const float* __restrict__ xp,
                                                    const float* __restrict__ xt,
                                                    float2* __restrict__ stl) {
    int tid = blockIdx.x * 256 + threadIdx.x;   // [0, 2*BB*CC)
    int c  = tid & (CC - 1);
    int rs = tid >> CSH;
    const float* x = (rs < BB ? xp : xt) + (long)(rs & (BB - 1)) * TT;
    long base = (long)c * LL;
    float buf[LL];
    const float4* xv = (const float4*)(x + base);
    #pragma unroll
    for (int i = 0; i < LL / 4; ++i) {
        float4 v = xv[i];
        buf[4 * i] = v.x; buf[4 * i + 1] = v.y;
        buf[4 * i + 2] = v.z; buf[4 * i + 3] = v.w;
    }
    float x1 = 0.f, x2 = 0.f;
    if (c > 0) { x1 = x[base - 1]; x2 = x[base - 2]; }
    float y1 = 0.f, y2 = 0.f;
    #pragma unroll
    for (int j = 0; j < LL; ++j)
        stepf(buf[j], x1, x2, y1, y2);
    stl[tid] = make_float2(y1, y2);
}

// ---------------------------------------------------------------------------
// Chain scan (IN-PLACE): per row (one wave each), convert per-chunk local
// end-states d_c into true chunk ENTRY states via s_{c+1} = d_c + M*s_c.
// Wave Hillis-Steele over lane digests (32 chunks/lane); M^k closed form.
// ---------------------------------------------------------------------------
__device__ __forceinline__ void Apow(double n, double* M) {
    const double a1 = -1.31861375911, a2 = 0.32059452332;
    double disc = sqrt(a1 * a1 - 4.0 * a2);
    double r1 = (-a1 + disc) * 0.5, r2 = (-a1 - disc) * 0.5;
    double inv = 1.0 / (r1 - r2);
    double p1a = pow(r1, n + 1.0), p2a = pow(r2, n + 1.0);
    double p1b = pow(r1, n),       p2b = pow(r2, n);
    double p1c = pow(r1, n - 1.0), p2c = pow(r2, n - 1.0);
    M[0] = (p1a - p2a) * inv;          // m00
    M[1] = -a2 * (p1b - p2b) * inv;    // m01
    M[2] = (p1b - p2b) * inv;          // m10
    M[3] = -a2 * (p1c - p2c) * inv;    // m11
}

__global__ __launch_bounds__(256) void k_chain(float2* __restrict__ buf) {
    int lane = threadIdx.x & 63;
    int row  = blockIdx.x * 4 + (threadIdx.x >> 6);   // [0, 2*BB)
    double A1[4]; Apow((double)LL, A1);
    float2* d = buf + (long)row * CC + lane * (CC / 64);
    // lane digest: exit state over CC/64 chunks given zero entry
    double v1 = 0.0, v2 = 0.0;
    #pragma unroll
    for (int i = 0; i < CC / 64; ++i) {
        float2 di = d[i];
        double n1 = (double)di.x + A1[0] * v1 + A1[1] * v2;
        double n2 = (double)di.y + A1[2] * v1 + A1[3] * v2;
        v1 = n1; v2 = n2;
    }
    // inclusive scan across lanes
    #pragma unroll
    for (int k = 1; k < 64; k <<= 1) {
        double Mk[4]; Apow((double)LL * (double)(CC / 64) * (double)k, Mk);
        double p1 = __shfl_up(v1, k);
        double p2 = __shfl_up(v2, k);
        if (lane >= k) {
            v1 = v1 + Mk[0] * p1 + Mk[1] * p2;
            v2 = v2 + Mk[2] * p1 + Mk[3] * p2;
        }
    }
    // exclusive prefix = entry state of this lane's first chunk
    double e1 = __shfl_up(v1, 1), e2 = __shfl_up(v2, 1);
    if (lane == 0) { e1 = 0.0; e2 = 0.0; }
    double s1 = e1, s2 = e2;
    #pragma unroll
    for (int i = 0; i < CC / 64; ++i) {
        float2 di = d[i];                                   // read BEFORE write
        d[i] = make_float2((float)s1, (float)s2);           // in-place overwrite
        double n1 = (double)di.x + A1[0] * s1 + A1[1] * s2;
        double n2 = (double)di.y + A1[2] * s1 + A1[3] * s2;
        s1 = n1; s2 = n2;
    }
}

// Recompute the two true forward outputs y[(cf+1)L], y[(cf+1)L+1] (the z-taps
// for a backward chunk) from x and the chained entry state of chunk cf+1.
__device__ __forceinline__ void ztaps(const float* x, long nb, float2 sn,
                                      float& z1, float& z2) {
    float xa = x[nb], xb = x[nb + 1], xm1 = x[nb - 1], xm2 = x[nb - 2];
    float f0 = fmaf(B0f, xa, fmaf(B1f, xm1, B2f * xm2));
    f0 = fmaf(P1f, sn.x, fmaf(P2f, sn.y, f0));
    float f1 = fmaf(B0f, xb, fmaf(B1f, xa, B2f * xm1));
    f1 = fmaf(P1f, f0, fmaf(P2f, sn.x, f1));
    z1 = f0; z2 = f1;
}

// ---------------------------------------------------------------------------
// Pass C: backward local end-states. Recompute TRUE forward outputs of chunk
// cf (seeded with chained entry state) into registers, run backward filter in
// reverse with zero w-state (true z taps); emit backward chunk-exit state.
// ---------------------------------------------------------------------------
__global__ __launch_bounds__(256) void k_bwd_states(const float* __restrict__ xp,
                                                    const float* __restrict__ xt,
                                                    const float2* __restrict__ sti_f,
                                                    float2* __restrict__ stl_b) {
    int tid = blockIdx.x * 256 + threadIdx.x;   // [0, 2*BB*CC)
    int c  = tid & (CC - 1);
    int rs = tid >> CSH;
    const float* x = (rs < BB ? xp : xt) + (long)(rs & (BB - 1)) * TT;
    int cf = CC - 1 - c;
    long base = (long)cf * LL;
    float2 sf = sti_f[(rs << CSH) + cf];
    float buf[LL];
    const float4* xv = (const float4*)(x + base);
    #pragma unroll
    for (int i = 0; i < LL / 4; ++i) {
        float4 v = xv[i];
        buf[4 * i] = v.x; buf[4 * i + 1] = v.y;
        buf[4 * i + 2] = v.z; buf[4 * i + 3] = v.w;
    }
    float x1 = 0.f, x2 = 0.f;
    if (cf > 0) { x1 = x[base - 1]; x2 = x[base - 2]; }
    float y1 = sf.x, y2 = sf.y;
    #pragma unroll
    for (int j = 0; j < LL; ++j)
        buf[j] = stepf(buf[j], x1, x2, y1, y2);   // buf now holds true y's
    float z1 = 0.f, z2 = 0.f;
    if (c > 0) {
        float2 sn = sti_f[(rs << CSH) + cf + 1];
        ztaps(x, base + LL, sn, z1, z2);
    }
    float w1 = 0.f, w2 = 0.f;
    #pragma unroll
    for (int j = LL - 1; j >= 0; --j)
        stepf(buf[j], z1, z2, w1, w2);
    stl_b[tid] = make_float2(w1, w2);
}

// ---------------------------------------------------------------------------
// Pass E: final pass. ONE signal per thread; lanes 0-31 of a wave handle p,
// lanes 32-63 handle t for the SAME (row, chunk). Recompute true forward
// outputs, run backward seeded with true backward entry state, clamp, then
// exchange clamped values with the partner lane (shfl_xor 32) and accumulate
// d^2 on BOTH lanes (total = 2x MSE numerator; scaled by 0.5 at finish).
// ---------------------------------------------------------------------------
__global__ __launch_bounds__(256) void k_final(const float* __restrict__ xp,
                                               const float* __restrict__ xt,
                                               const float2* __restrict__ sti_f,
                                               const float2* __restrict__ sti_b,
                                               float* __restrict__ acc) {
    int tid = blockIdx.x * 256 + threadIdx.x;   // [0, 2*BB*CC)
    int lane = threadIdx.x & 63;
    int w = tid >> 6;
    int item = (w << 5) + (lane & 31);          // [0, BB*CC)
    int sig = lane >> 5;
    int c = item & (CC - 1);
    int r = item >> CSH;
    int cf = CC - 1 - c;
    long base = (long)cf * LL;
    const float* x = (sig ? xt : xp) + (long)r * TT;
    int row = (sig ? BB + r : r);

    float buf[LL];
    const float4* xv = (const float4*)(x + base);
    #pragma unroll
    for (int i = 0; i < LL / 4; ++i) {
        float4 v = xv[i];
        buf[4 * i] = v.x; buf[4 * i + 1] = v.y;
        buf[4 * i + 2] = v.z; buf[4 * i + 3] = v.w;
    }
    float2 sf = sti_f[((long)row << CSH) + cf];
    float x1 = 0.f, x2 = 0.f;
    if (cf > 0) { x1 = x[base - 1]; x2 = x[base - 2]; }
    float y1 = sf.x, y2 = sf.y;
    #pragma unroll
    for (int j = 0; j < LL; ++j)
        buf[j] = stepf(buf[j], x1, x2, y1, y2);   // true forward y's
    float z1 = 0.f, z2 = 0.f;
    if (c > 0) {
        float2 sn = sti_f[((long)row << CSH) + cf + 1];
        ztaps(x, base + LL, sn, z1, z2);
    }
    float2 sb = sti_b[((long)row << CSH) + c];
    float w1 = sb.x, w2 = sb.y;
    float accl = 0.f;
    #pragma unroll
    for (int j = LL - 1; j >= 0; --j) {
        float wv = stepf(buf[j], z1, z2, w1, w2);
        float cl = fminf(fmaxf(wv, -1.f), 1.f);
        float other = __shfl_xor(cl, 32);
        float d = cl - other;
        accl = fmaf(d, d, accl);
    }
    // wave reduce (width 64) then cross-wave via LDS
    for (int off = 32; off > 0; off >>= 1) accl += __shfl_down(accl, off);
    __shared__ float wsum[4];
    if ((threadIdx.x & 63) == 0) wsum[threadIdx.x >> 6] = accl;
    __syncthreads();
    if (threadIdx.x == 0)
        atomicAdd(acc, wsum[0] + wsum[1] + wsum[2] + wsum[3]);
}

__global__ void k_finish(const float* __restrict__ acc, float* __restrict__ out) {
    // acc holds 2x the squared-diff sum (both partner lanes accumulate d^2)
    out[0] = acc[0] * (0.5f / (float)((long)BB * TT));
}

extern "C" void kernel_launch(void* const* d_in, const int* in_sizes, int n_in,
                              void* d_out, int out_size, void* d_ws, size_t ws_size,
                              hipStream_t stream) {
    const float* xp = (const float*)d_in[0];
    const float* xt = (const float*)d_in[1];
    float* out = (float*)d_out;

    // Workspace: 2 state arrays (chain runs in-place) of 2*BB*CC float2 = 8 MB
    // each, + acc scalar.
    const size_t one_st = (size_t)2 * BB * CC * sizeof(float2);
    char* w = (char*)d_ws;
    float2* S1 = (float2*)w;                 w += one_st;   // fwd states
    float2* S2 = (float2*)w;                 w += one_st;   // bwd states
    float*  acc  = (float*)w;

    hipMemsetAsync(acc, 0, sizeof(float), stream);

    const int nA = 2 * BB * CC;   // 1,048,576 threads for per-chunk passes
    k_fwd_states<<<nA / 256, 256, 0, stream>>>(xp, xt, S1);
    k_chain<<<(2 * BB) / 4, 256, 0, stream>>>(S1);          // S1 -> entry states
    k_bwd_states<<<nA / 256, 256, 0, stream>>>(xp, xt, S1, S2);
    k_chain<<<(2 * BB) / 4, 256, 0, stream>>>(S2);          // S2 -> entry states
    k_final<<<nA / 256, 256, 0, stream>>>(xp, xt, S1, S2, acc);
    k_finish<<<1, 1, 0, stream>>>(acc, out);
}

// Round 4
// 263.121 us; speedup vs baseline: 1.0001x; 1.0001x over previous
//
#include <hip/hip_runtime.h>

// Problem constants (fixed by reference setup_inputs)
#define BB 256          // batch
#define TT 65536        // time
#define LL 32           // chunk length (register-buffered: 8 x float4)
#define CC (TT / LL)    // 2048 chunks per row
#define CSH 11          // log2(CC)

// Filter coefficients (a0 = 1)
#define P1f  ( 1.31861375911f)   // -a1
#define P2f  (-0.32059452332f)   // -a2
#define B0f  ( 0.95616638497f)
#define B1f  (-1.31960414122f)
#define B2f  ( 0.36343775625f)

// One IIR step: y = b0*x + b1*x1 + b2*x2 - a1*y1 - a2*y2; shift state.
__device__ __forceinline__ float stepf(float xc, float& x1, float& x2,
                                       float& y1, float& y2) {
    float fir = fmaf(B0f, xc, fmaf(B1f, x1, B2f * x2));
    float y   = fmaf(P1f, y1, fmaf(P2f, y2, fir));
    y2 = y1; y1 = y;
    x2 = x1; x1 = xc;
    return y;
}

// Forward-step a float4 in place (overwrites components with filter outputs).
#define FWD4(q) { (q).x = stepf((q).x, x1, x2, y1, y2); \
                  (q).y = stepf((q).y, x1, x2, y1, y2); \
                  (q).z = stepf((q).z, x1, x2, y1, y2); \
                  (q).w = stepf((q).w, x1, x2, y1, y2); }
// Forward-step, discard outputs (state-only pass).
#define FWD4D(q) { stepf((q).x, x1, x2, y1, y2); stepf((q).y, x1, x2, y1, y2); \
                   stepf((q).z, x1, x2, y1, y2); stepf((q).w, x1, x2, y1, y2); }
// Backward-step (reverse element order), discard outputs.
#define BWD4D(q) { stepf((q).w, z1, z2, w1, w2); stepf((q).z, z1, z2, w1, w2); \
                   stepf((q).y, z1, z2, w1, w2); stepf((q).x, z1, z2, w1, w2); }
// Backward-step with clamp + partner-lane diff + accumulate.
#define BSTEP(v) { float wv = stepf((v), z1, z2, w1, w2); \
                   float cl = fminf(fmaxf(wv, -1.f), 1.f); \
                   float ot = __shfl_xor(cl, 32); \
                   float dd = cl - ot; accl = fmaf(dd, dd, accl); }
#define BWD4A(q) { BSTEP((q).w) BSTEP((q).z) BSTEP((q).y) BSTEP((q).x) }

#define LOADQ(xv) float4 q0 = (xv)[0], q1 = (xv)[1], q2 = (xv)[2], q3 = (xv)[3], \
                         q4 = (xv)[4], q5 = (xv)[5], q6 = (xv)[6], q7 = (xv)[7];

// ---------------------------------------------------------------------------
// Pass A: forward local end-states. Thread = (signal-row rs, chunk c).
// Zero y-state, TRUE x taps; emits chunk-exit state (y[last], y[last-1]).
// ---------------------------------------------------------------------------
__global__ __launch_bounds__(256) void k_fwd_states(const float* __restrict__ xp,
                                                    const float* __restrict__ xt,
                                                    float2* __restrict__ stl) {
    int tid = blockIdx.x * 256 + threadIdx.x;   // [0, 2*BB*CC)
    int c  = tid & (CC - 1);
    int rs = tid >> CSH;
    const float* x = (rs < BB ? xp : xt) + (long)(rs & (BB - 1)) * TT;
    long base = (long)c * LL;
    const float4* xv = (const float4*)(x + base);
    LOADQ(xv);
    float x1 = 0.f, x2 = 0.f;
    if (c > 0) { x1 = x[base - 1]; x2 = x[base - 2]; }
    float y1 = 0.f, y2 = 0.f;
    FWD4D(q0) FWD4D(q1) FWD4D(q2) FWD4D(q3)
    FWD4D(q4) FWD4D(q5) FWD4D(q6) FWD4D(q7)
    stl[tid] = make_float2(y1, y2);
}

// ---------------------------------------------------------------------------
// Chain scan (IN-PLACE): per row (one wave each), convert per-chunk local
// end-states d_c into true chunk ENTRY states via s_{c+1} = d_c + M*s_c.
// Wave Hillis-Steele over lane digests (CC/64 chunks/lane); M^k closed form.
// ---------------------------------------------------------------------------
__device__ __forceinline__ void Apow(double n, double* M) {
    const double a1 = -1.31861375911, a2 = 0.32059452332;
    double disc = sqrt(a1 * a1 - 4.0 * a2);
    double r1 = (-a1 + disc) * 0.5, r2 = (-a1 - disc) * 0.5;
    double inv = 1.0 / (r1 - r2);
    double p1a = pow(r1, n + 1.0), p2a = pow(r2, n + 1.0);
    double p1b = pow(r1, n),       p2b = pow(r2, n);
    double p1c = pow(r1, n - 1.0), p2c = pow(r2, n - 1.0);
    M[0] = (p1a - p2a) * inv;          // m00
    M[1] = -a2 * (p1b - p2b) * inv;    // m01
    M[2] = (p1b - p2b) * inv;          // m10
    M[3] = -a2 * (p1c - p2c) * inv;    // m11
}

__global__ __launch_bounds__(256) void k_chain(float2* __restrict__ buf) {
    int lane = threadIdx.x & 63;
    int row  = blockIdx.x * 4 + (threadIdx.x >> 6);   // [0, 2*BB)
    double A1[4]; Apow((double)LL, A1);
    float2* d = buf + (long)row * CC + lane * (CC / 64);
    // lane digest: exit state over CC/64 chunks given zero entry
    double v1 = 0.0, v2 = 0.0;
    #pragma unroll
    for (int i = 0; i < CC / 64; ++i) {
        float2 di = d[i];
        double n1 = (double)di.x + A1[0] * v1 + A1[1] * v2;
        double n2 = (double)di.y + A1[2] * v1 + A1[3] * v2;
        v1 = n1; v2 = n2;
    }
    // inclusive scan across lanes
    #pragma unroll
    for (int k = 1; k < 64; k <<= 1) {
        double Mk[4]; Apow((double)LL * (double)(CC / 64) * (double)k, Mk);
        double p1 = __shfl_up(v1, k);
        double p2 = __shfl_up(v2, k);
        if (lane >= k) {
            v1 = v1 + Mk[0] * p1 + Mk[1] * p2;
            v2 = v2 + Mk[2] * p1 + Mk[3] * p2;
        }
    }
    // exclusive prefix = entry state of this lane's first chunk
    double e1 = __shfl_up(v1, 1), e2 = __shfl_up(v2, 1);
    if (lane == 0) { e1 = 0.0; e2 = 0.0; }
    double s1 = e1, s2 = e2;
    #pragma unroll
    for (int i = 0; i < CC / 64; ++i) {
        float2 di = d[i];                                   // read BEFORE write
        d[i] = make_float2((float)s1, (float)s2);           // in-place overwrite
        double n1 = (double)di.x + A1[0] * s1 + A1[1] * s2;
        double n2 = (double)di.y + A1[2] * s1 + A1[3] * s2;
        s1 = n1; s2 = n2;
    }
}

// Recompute the two true forward outputs y[(cf+1)L], y[(cf+1)L+1] (the z-taps
// for a backward chunk) from x-taps and the chained entry state of chunk cf+1.
// xm1 = x[(cf+1)L - 1], xm2 = x[(cf+1)L - 2] (original x of this chunk's tail).
__device__ __forceinline__ void ztaps(const float* x, long nb, float2 sn,
                                      float xm1, float xm2,
                                      float& z1, float& z2) {
    float xa = x[nb], xb = x[nb + 1];
    float f0 = fmaf(B0f, xa, fmaf(B1f, xm1, B2f * xm2));
    f0 = fmaf(P1f, sn.x, fmaf(P2f, sn.y, f0));
    float f1 = fmaf(B0f, xb, fmaf(B1f, xa, B2f * xm1));
    f1 = fmaf(P1f, f0, fmaf(P2f, sn.x, f1));
    z1 = f0; z2 = f1;
}

// ---------------------------------------------------------------------------
// Pass C: backward local end-states. Recompute TRUE forward outputs of chunk
// cf (seeded with chained entry state) into registers, run backward filter in
// reverse with zero w-state (true z taps); emit backward chunk-exit state.
// ---------------------------------------------------------------------------
__global__ __launch_bounds__(256) void k_bwd_states(const float* __restrict__ xp,
                                                    const float* __restrict__ xt,
                                                    const float2* __restrict__ sti_f,
                                                    float2* __restrict__ stl_b) {
    int tid = blockIdx.x * 256 + threadIdx.x;   // [0, 2*BB*CC)
    int c  = tid & (CC - 1);
    int rs = tid >> CSH;
    const float* x = (rs < BB ? xp : xt) + (long)(rs & (BB - 1)) * TT;
    int cf = CC - 1 - c;
    long base = (long)cf * LL;
    const float4* xv = (const float4*)(x + base);
    LOADQ(xv);
    float2 sf = sti_f[(rs << CSH) + cf];
    float x1 = 0.f, x2 = 0.f;
    if (cf > 0) { x1 = x[base - 1]; x2 = x[base - 2]; }
    float xl1 = q7.w, xl2 = q7.z;               // original x tail (for ztaps)
    float y1 = sf.x, y2 = sf.y;
    FWD4(q0) FWD4(q1) FWD4(q2) FWD4(q3)
    FWD4(q4) FWD4(q5) FWD4(q6) FWD4(q7)         // q's now hold true y's
    float z1 = 0.f, z2 = 0.f;
    if (c > 0) {
        float2 sn = sti_f[(rs << CSH) + cf + 1];
        ztaps(x, base + LL, sn, xl1, xl2, z1, z2);
    }
    float w1 = 0.f, w2 = 0.f;
    BWD4D(q7) BWD4D(q6) BWD4D(q5) BWD4D(q4)
    BWD4D(q3) BWD4D(q2) BWD4D(q1) BWD4D(q0)
    stl_b[tid] = make_float2(w1, w2);
}

// ---------------------------------------------------------------------------
// Pass E: final pass. ONE signal per thread; lanes 0-31 of a wave handle p,
// lanes 32-63 handle t for the SAME (row, chunk). Recompute true forward
// outputs, run backward seeded with true backward entry state, clamp, then
// exchange clamped values with the partner lane (shfl_xor 32) and accumulate
// d^2 on BOTH lanes (total = 2x MSE numerator; scaled by 0.5 at finish).
// ---------------------------------------------------------------------------
__global__ __launch_bounds__(256) void k_final(const float* __restrict__ xp,
                                               const float* __restrict__ xt,
                                               const float2* __restrict__ sti_f,
                                               const float2* __restrict__ sti_b,
                                               float* __restrict__ acc) {
    int tid = blockIdx.x * 256 + threadIdx.x;   // [0, 2*BB*CC)
    int lane = threadIdx.x & 63;
    int w = tid >> 6;
    int item = (w << 5) + (lane & 31);          // [0, BB*CC)
    int sig = lane >> 5;
    int c = item & (CC - 1);
    int r = item >> CSH;
    int cf = CC - 1 - c;
    long base = (long)cf * LL;
    const float* x = (sig ? xt : xp) + (long)r * TT;
    int row = (sig ? BB + r : r);

    const float4* xv = (const float4*)(x + base);
    LOADQ(xv);
    float2 sf = sti_f[((long)row << CSH) + cf];
    float x1 = 0.f, x2 = 0.f;
    if (cf > 0) { x1 = x[base - 1]; x2 = x[base - 2]; }
    float xl1 = q7.w, xl2 = q7.z;               // original x tail (for ztaps)
    float y1 = sf.x, y2 = sf.y;
    FWD4(q0) FWD4(q1) FWD4(q2) FWD4(q3)
    FWD4(q4) FWD4(q5) FWD4(q6) FWD4(q7)         // q's now hold true y's
    float z1 = 0.f, z2 = 0.f;
    if (c > 0) {
        float2 sn = sti_f[((long)row << CSH) + cf + 1];
        ztaps(x, base + LL, sn, xl1, xl2, z1, z2);
    }
    float2 sb = sti_b[((long)row << CSH) + c];
    float w1 = sb.x, w2 = sb.y;
    float accl = 0.f;
    BWD4A(q7) BWD4A(q6) BWD4A(q5) BWD4A(q4)
    BWD4A(q3) BWD4A(q2) BWD4A(q1) BWD4A(q0)
    // wave reduce (width 64) then cross-wave via LDS
    for (int off = 32; off > 0; off >>= 1) accl += __shfl_down(accl, off);
    __shared__ float wsum[4];
    if ((threadIdx.x & 63) == 0) wsum[threadIdx.x >> 6] = accl;
    __syncthreads();
    if (threadIdx.x == 0)
        atomicAdd(acc, wsum[0] + wsum[1] + wsum[2] + wsum[3]);
}

__global__ void k_finish(const float* __restrict__ acc, float* __restrict__ out) {
    // acc holds 2x the squared-diff sum (both partner lanes accumulate d^2)
    out[0] = acc[0] * (0.5f / (float)((long)BB * TT));
}

extern "C" void kernel_launch(void* const* d_in, const int* in_sizes, int n_in,
                              void* d_out, int out_size, void* d_ws, size_t ws_size,
                              hipStream_t stream) {
    const float* xp = (const float*)d_in[0];
    const float* xt = (const float*)d_in[1];
    float* out = (float*)d_out;

    // Workspace: 2 state arrays (chain runs in-place) of 2*BB*CC float2 = 8 MB
    // each, + acc scalar.
    const size_t one_st = (size_t)2 * BB * CC * sizeof(float2);
    char* w = (char*)d_ws;
    float2* S1 = (float2*)w;                 w += one_st;   // fwd states
    float2* S2 = (float2*)w;                 w += one_st;   // bwd states
    float*  acc  = (float*)w;

    hipMemsetAsync(acc, 0, sizeof(float), stream);

    const int nA = 2 * BB * CC;   // 1,048,576 threads for per-chunk passes
    k_fwd_states<<<nA / 256, 256, 0, stream>>>(xp, xt, S1);
    k_chain<<<(2 * BB) / 4, 256, 0, stream>>>(S1);          // S1 -> entry states
    k_bwd_states<<<nA / 256, 256, 0, stream>>>(xp, xt, S1, S2);
    k_chain<<<(2 * BB) / 4, 256, 0, stream>>>(S2);          // S2 -> entry states
    k_final<<<nA / 256, 256, 0, stream>>>(xp, xt, S1, S2, acc);
    k_finish<<<1, 1, 0, stream>>>(acc, out);
}